// Round 9
// baseline (172.975 us; speedup 1.0000x reference)
//
#include <hip/hip_runtime.h>

// ---------------------------------------------------------------------------
// HierarchicalAffinityLoss on MI355X, fp16-MFMA, round 9.
// loss = mean_r relu(maxDot_diff(r) - minDot_same(r) + 0.3), dots of
// row-normalized embeddings. Self-exclusion dropped (self-dot=1.0 never the
// min over ~2000 same-family dots near 0; verified rounds 3-8, absmax 0.0).
// Round-9: round-8 per-wave structure (no LDS, direct global->VGPR frags,
// triangle tiles with dual row/col extremes) but packed into FEW long-lived
// workgroups: 768 wgs x 4 waves, each wave a contiguous ~2.7-task span.
// Round-8 evidence: 8256 single-wave wgs ran at the wg-dispatch rate
// (~110 wg/us, occupancy 9.8%) -- dispatch starvation, not memory.
// prep also re-packed (256 wgs, grid-stride) for the same reason.
// ---------------------------------------------------------------------------

typedef __attribute__((ext_vector_type(8))) _Float16 half8;  // MFMA A/B frag
typedef __attribute__((ext_vector_type(4))) float floatx4;   // MFMA C/D
typedef __attribute__((ext_vector_type(4))) unsigned short ushort4v;

constexpr int D = 256;   // embedding dim
#define MARGIN 0.3f
// packed family table {0,1,2,1,3,3}, 3 bits each
#define FAM_PACKED 111240

static __device__ __forceinline__ unsigned packmm(float mn, float mx) {
  unsigned lo = __builtin_bit_cast(unsigned short, (_Float16)mn);
  unsigned hi = __builtin_bit_cast(unsigned short, (_Float16)mx);
  return lo | (hi << 16);
}

// K1: grid-stride waves -> Eh[row][:] = fp16(E/||E||), fam[row]; zero accums
__global__ __launch_bounds__(256) void prep_kernel(
    const float* __restrict__ E, const int* __restrict__ labels,
    unsigned short* __restrict__ Eh, int* __restrict__ fam,
    float* __restrict__ sumAcc, int* __restrict__ cntAcc,
    int* __restrict__ doneCnt, int B) {
  if (blockIdx.x == 0 && threadIdx.x == 0) {
    sumAcc[0] = 0.0f; cntAcc[0] = 0; doneCnt[0] = 0;
  }
  int wave = blockIdx.x * 4 + (threadIdx.x >> 6);
  int lane = threadIdx.x & 63;
  int nw   = gridDim.x * 4;
  for (int row = wave; row < B; row += nw) {
    float4 v = *(const float4*)&E[(long)row * D + lane * 4];
    float s = v.x * v.x + v.y * v.y + v.z * v.z + v.w * v.w;
#pragma unroll
    for (int o = 1; o < 64; o <<= 1) s += __shfl_xor(s, o);
    float rn = 1.0f / sqrtf(s);
    ushort4v o4;
    o4.x = __builtin_bit_cast(unsigned short, (_Float16)(v.x * rn));
    o4.y = __builtin_bit_cast(unsigned short, (_Float16)(v.y * rn));
    o4.z = __builtin_bit_cast(unsigned short, (_Float16)(v.z * rn));
    o4.w = __builtin_bit_cast(unsigned short, (_Float16)(v.w * rn));
    *(ushort4v*)&Eh[(long)row * D + lane * 4] = o4;
    if (lane == 0) {
      int lab = labels[row];
      int labc = lab < 0 ? 0 : (lab > 5 ? 5 : lab);
      fam[row] = (lab < 6) ? ((FAM_PACKED >> (3 * labc)) & 7) : -1;
    }
  }
}

// K2: 4 independent waves per wg; each wave owns a contiguous span of
// upper-triangle 64x64 tiles; fragments direct global->VGPR, no LDS.
__global__ __launch_bounds__(256) void gram_kernel(
    const unsigned short* __restrict__ Eh, const int* __restrict__ fam,
    unsigned* __restrict__ partial, int nt, int nTasks) {
  const int l = threadIdx.x & 63;
  const int m = l & 15, q = l >> 4;
  const int gw = blockIdx.x * 4 + (threadIdx.x >> 6);   // global wave id
  const int nw = gridDim.x * 4;

  const int t0 = (int)(((long)gw * nTasks) / nw);
  const int t1 = (int)(((long)(gw + 1) * nTasks) / nw);

  // decode t0 -> (rt, ct), rt-major triangle order (rt <= ct)
  int rt = 0, ct;
  {
    int tau = t0, rowlen = nt;
    while (tau >= rowlen) { tau -= rowlen; rowlen--; rt++; }
    ct = rt + tau;
  }

  for (int task = t0; task < t1; ++task) {
    const int r0 = rt * 64, c0 = ct * 64;
    const int famv  = fam[r0 + l];   // fam of row r0+l
    const int famcv = fam[c0 + l];   // fam of col c0+l
    // frag base: lane reads row (sub*16+m), k-chunk q*8
    const unsigned short* Abase = Eh + ((long)r0 + m) * D + q * 8;
    const unsigned short* Bbase = Eh + ((long)c0 + m) * D + q * 8;

    floatx4 acc[4][4];
#pragma unroll
    for (int mi = 0; mi < 4; ++mi)
#pragma unroll
      for (int nj = 0; nj < 4; ++nj) acc[mi][nj] = (floatx4)0.0f;

    // K = 256 = 8 steps of 32; loads independent, compiler pipelines.
#pragma unroll
    for (int ks = 0; ks < 8; ++ks) {
      const int ko = ks * 32;
      half8 a[4], b[4];
#pragma unroll
      for (int mi = 0; mi < 4; ++mi)
        a[mi] = *(const half8*)&Abase[(long)mi * 16 * D + ko];
#pragma unroll
      for (int nj = 0; nj < 4; ++nj)
        b[nj] = *(const half8*)&Bbase[(long)nj * 16 * D + ko];
#pragma unroll
      for (int mi = 0; mi < 4; ++mi)
#pragma unroll
        for (int nj = 0; nj < 4; ++nj)
          acc[mi][nj] = __builtin_amdgcn_mfma_f32_16x16x32_f16(
              a[mi], b[nj], acc[mi][nj], 0, 0, 0);
    }

    // ---- fused epilogue: row-side and col-side masked extremes ----
    int famR[16], famC[4];
#pragma unroll
    for (int mi = 0; mi < 4; ++mi)
#pragma unroll
      for (int r = 0; r < 4; ++r)
        famR[mi * 4 + r] = __shfl(famv, mi * 16 + q * 4 + r);
#pragma unroll
    for (int nj = 0; nj < 4; ++nj) famC[nj] = __shfl(famcv, nj * 16 + m);

    float rMin[16], rMax[16], cMin[4], cMax[4];
#pragma unroll
    for (int i = 0; i < 16; ++i) { rMin[i] = 4.0f; rMax[i] = -4.0f; }
#pragma unroll
    for (int j = 0; j < 4; ++j) { cMin[j] = 4.0f; cMax[j] = -4.0f; }

#pragma unroll
    for (int mi = 0; mi < 4; ++mi)
#pragma unroll
      for (int nj = 0; nj < 4; ++nj)
#pragma unroll
        for (int r = 0; r < 4; ++r) {
          float d = acc[mi][nj][r];          // C/D: col=l&15, row=q*4+r
          bool same = (famR[mi * 4 + r] == famC[nj]);
          float ds = same ? d : 4.0f;
          float dd = same ? -4.0f : d;
          rMin[mi * 4 + r] = fminf(rMin[mi * 4 + r], ds);
          rMax[mi * 4 + r] = fmaxf(rMax[mi * 4 + r], dd);
          cMin[nj] = fminf(cMin[nj], ds);
          cMax[nj] = fmaxf(cMax[nj], dd);
        }

    // row-side: reduce across the 16 col lanes (xor over m bits)
#pragma unroll
    for (int o = 1; o < 16; o <<= 1)
#pragma unroll
      for (int i = 0; i < 16; ++i) {
        rMin[i] = fminf(rMin[i], __shfl_xor(rMin[i], o));
        rMax[i] = fmaxf(rMax[i], __shfl_xor(rMax[i], o));
      }
    if (m == 0) {
      unsigned* dst = partial + ((long)rt * nt + ct) * 64;
#pragma unroll
      for (int mi = 0; mi < 4; ++mi)
#pragma unroll
        for (int r = 0; r < 4; ++r)
          dst[mi * 16 + q * 4 + r] = packmm(rMin[mi * 4 + r], rMax[mi * 4 + r]);
    }
    // col-side: reduce across the 4 q lanes (xor 16, 32); skip diagonal
#pragma unroll
    for (int o = 16; o < 64; o <<= 1)
#pragma unroll
      for (int j = 0; j < 4; ++j) {
        cMin[j] = fminf(cMin[j], __shfl_xor(cMin[j], o));
        cMax[j] = fmaxf(cMax[j], __shfl_xor(cMax[j], o));
      }
    if (q == 0 && rt != ct) {
      unsigned* dst = partial + ((long)ct * nt + rt) * 64;
#pragma unroll
      for (int nj = 0; nj < 4; ++nj)
        dst[nj * 16 + m] = packmm(cMin[nj], cMax[nj]);
    }

    // advance along the triangle (rt-major)
    if (++ct == nt) { ++rt; ct = rt; }
  }
}

// K3: 4 threads per row combine nt contributor slots; grid reduce; last
// block writes the final mean (done-counter pattern).
__global__ __launch_bounds__(256) void reduce_kernel(
    const unsigned* __restrict__ partial, float* __restrict__ sumAcc,
    int* __restrict__ cntAcc, int* __restrict__ doneCnt,
    float* __restrict__ out, int B, int nt) {
  int gid = blockIdx.x * 256 + threadIdx.x;
  int row = gid >> 2;            // 4 threads per row
  int c   = gid & 3;
  int t = row >> 6, rl = row & 63;
  const unsigned* base = partial + ((long)t * nt) * 64 + rl;
  float mn = 4.0f, mx = -4.0f;
#pragma unroll 8
  for (int k = c; k < nt; k += 4) {
    unsigned p = base[(long)k * 64];
    mn = fminf(mn, (float)__builtin_bit_cast(_Float16,
                                             (unsigned short)(p & 0xFFFF)));
    mx = fmaxf(mx, (float)__builtin_bit_cast(_Float16,
                                             (unsigned short)(p >> 16)));
  }
  // combine the 4 contributor lanes
#pragma unroll
  for (int o = 1; o < 4; o <<= 1) {
    mn = fminf(mn, __shfl_xor(mn, o));
    mx = fmaxf(mx, __shfl_xor(mx, o));
  }
  float loss = 0.0f;
  int cc = 0;
  if (c == 0 && mn < 3.0f && mx > -3.0f) {   // has same && has diff
    loss = fmaxf(mx - mn + MARGIN, 0.0f);
    cc = 1;
  }
#pragma unroll
  for (int o = 1; o < 64; o <<= 1) {
    loss += __shfl_xor(loss, o);
    cc   += __shfl_xor(cc, o);
  }
  __shared__ float ls[4];
  __shared__ int   cs[4];
  if ((threadIdx.x & 63) == 0) {
    ls[threadIdx.x >> 6] = loss;
    cs[threadIdx.x >> 6] = cc;
  }
  __syncthreads();
  if (threadIdx.x == 0) {
    atomicAdd(sumAcc, ls[0] + ls[1] + ls[2] + ls[3]);
    atomicAdd(cntAcc, cs[0] + cs[1] + cs[2] + cs[3]);
    __threadfence();
    int old = atomicAdd(doneCnt, 1);
    if (old == (int)gridDim.x - 1) {
      float S = atomicAdd(sumAcc, 0.0f);   // coherent read
      int   C = atomicAdd(cntAcc, 0);
      out[0] = S / (float)(C > 0 ? C : 1);
    }
  }
}

extern "C" void kernel_launch(void* const* d_in, const int* in_sizes, int n_in,
                              void* d_out, int out_size, void* d_ws, size_t ws_size,
                              hipStream_t stream) {
  const float* E      = (const float*)d_in[0];
  const int*   labels = (const int*)d_in[1];
  float*       out    = (float*)d_out;
  const int B  = in_sizes[1];        // 8192
  const int nt = B / 64;             // 128 row tiles
  const int nTasks = nt * (nt + 1) / 2;   // 8256 triangle tiles

  // ws: Eh[B*D] fp16 (4MB) | fam[B] | partial[nt*nt*64] uint (4MB) | accums
  unsigned short* Eh = (unsigned short*)d_ws;
  int* fam           = (int*)(Eh + (size_t)B * D);
  unsigned* partial  = (unsigned*)(fam + B);
  float* sumAcc      = (float*)(partial + (size_t)nt * nt * 64);
  int* cntAcc        = (int*)(sumAcc + 1);
  int* doneCnt       = cntAcc + 1;

  prep_kernel<<<dim3(256), 256, 0, stream>>>(E, labels, Eh, fam,
                                             sumAcc, cntAcc, doneCnt, B);
  gram_kernel<<<dim3(768), 256, 0, stream>>>(Eh, fam, partial, nt, nTasks);
  reduce_kernel<<<dim3(B * 4 / 256), 256, 0, stream>>>(partial, sumAcc, cntAcc,
                                                       doneCnt, out, B, nt);
}

// Round 10
// 147.781 us; speedup vs baseline: 1.1705x; 1.1705x over previous
//
#include <hip/hip_runtime.h>

// ---------------------------------------------------------------------------
// HierarchicalAffinityLoss on MI355X, fp16-MFMA, round 10.
// loss = mean_r relu(maxDot_diff(r) - minDot_same(r) + 0.3), dots of
// row-normalized embeddings. Self-exclusion dropped (self-dot=1.0 never the
// min over ~2000 same-family dots near 0; verified rounds 3-9, absmax 0.0).
// Round-10: cut operand traffic 8x. Evidence: R3/R5/R7/R8/R9 all moved
// ~525 MB (private A+B per 64x64 task) and all ran at 8-11.5 B/cyc/CU
// regardless of structure -> per-CU vector-memory delivery is the wall.
// Fix: 4-wave blocks own a 256-row A-panel IN REGISTERS (loaded once,
// 128 VGPR/lane); B-tiles (32 KB) staged once per block-task into
// double-buffered LDS and shared by all 4 waves => 66 MB total traffic.
// Barrier is per-task with a full task of prefetch overlap.
// ---------------------------------------------------------------------------

typedef __attribute__((ext_vector_type(8))) _Float16 half8;  // MFMA A/B frag
typedef __attribute__((ext_vector_type(4))) float floatx4;   // MFMA C/D
typedef __attribute__((ext_vector_type(4))) unsigned short ushort4v;

constexpr int D = 256;   // embedding dim
#define MARGIN 0.3f
// packed family table {0,1,2,1,3,3}, 3 bits each
#define FAM_PACKED 111240

// async 16B global -> LDS (wave-uniform LDS base + lane*16)
static __device__ __forceinline__ void ld_g2l16(const unsigned short* g,
                                                unsigned short* l) {
  __builtin_amdgcn_global_load_lds(
      (const __attribute__((address_space(1))) unsigned int*)(const void*)g,
      (__attribute__((address_space(3))) unsigned int*)(void*)l, 16, 0, 0);
}

static __device__ __forceinline__ unsigned packmm(float mn, float mx) {
  unsigned lo = __builtin_bit_cast(unsigned short, (_Float16)mn);
  unsigned hi = __builtin_bit_cast(unsigned short, (_Float16)mx);
  return lo | (hi << 16);
}

// K1: grid-stride waves -> Eh[row][:] = fp16(E/||E||), fam[row]; zero accums
__global__ __launch_bounds__(256) void prep_kernel(
    const float* __restrict__ E, const int* __restrict__ labels,
    unsigned short* __restrict__ Eh, int* __restrict__ fam,
    float* __restrict__ sumAcc, int* __restrict__ cntAcc,
    int* __restrict__ doneCnt, int B) {
  if (blockIdx.x == 0 && threadIdx.x == 0) {
    sumAcc[0] = 0.0f; cntAcc[0] = 0; doneCnt[0] = 0;
  }
  int wave = blockIdx.x * 4 + (threadIdx.x >> 6);
  int lane = threadIdx.x & 63;
  int nw   = gridDim.x * 4;
  for (int row = wave; row < B; row += nw) {
    float4 v = *(const float4*)&E[(long)row * D + lane * 4];
    float s = v.x * v.x + v.y * v.y + v.z * v.z + v.w * v.w;
#pragma unroll
    for (int o = 1; o < 64; o <<= 1) s += __shfl_xor(s, o);
    float rn = 1.0f / sqrtf(s);
    ushort4v o4;
    o4.x = __builtin_bit_cast(unsigned short, (_Float16)(v.x * rn));
    o4.y = __builtin_bit_cast(unsigned short, (_Float16)(v.y * rn));
    o4.z = __builtin_bit_cast(unsigned short, (_Float16)(v.z * rn));
    o4.w = __builtin_bit_cast(unsigned short, (_Float16)(v.w * rn));
    *(ushort4v*)&Eh[(long)row * D + lane * 4] = o4;
    if (lane == 0) {
      int lab = labels[row];
      int labc = lab < 0 ? 0 : (lab > 5 ? 5 : lab);
      fam[row] = (lab < 6) ? ((FAM_PACKED >> (3 * labc)) & 7) : -1;
    }
  }
}

// K2: block = 4 waves, owns 256-row A-panel (in registers, wave w holds
// row-tile rt = 4*rb + w). Tasks: (rb, ct) with ct in [4rb, nt); wave
// computes tile (rt, ct) iff rt <= ct (triangle). B-tile per task staged
// into double-buffered LDS shared by all waves.
__global__ __launch_bounds__(256) void gram_kernel(
    const unsigned short* __restrict__ Eh, const int* __restrict__ fam,
    unsigned* __restrict__ partial, int nt, int nTasks) {
  __shared__ unsigned short Bs[2][64 * 256];   // 2 x 32 KB

  const int tid = threadIdx.x;
  const int w   = tid >> 6;
  const int l   = tid & 63;
  const int m   = l & 15, q = l >> 4;

  const int t0 = (int)(((long)blockIdx.x * nTasks) / gridDim.x);
  const int t1 = (int)(((long)(blockIdx.x + 1) * nTasks) / gridDim.x);

  // decode t0 -> (rb, ct): C(r) = r*(nt - 2r + 2) tasks before row-block r
  int rb = 0;
  while ((rb + 1) * (nt - 2 * (rb + 1) + 2) <= t0) ++rb;
  int ct = 4 * rb + (t0 - rb * (nt - 2 * rb + 2));

  half8 apan[8][4];
  int famv;
  int rt = 4 * rb + w;

  // load A-panel + row fams for current rb (per wave, registers)
  {
    const int r0w = rt * 64;
#pragma unroll
    for (int ks = 0; ks < 8; ++ks)
#pragma unroll
      for (int mi = 0; mi < 4; ++mi)
        apan[ks][mi] =
            *(const half8*)&Eh[(long)(r0w + mi * 16 + m) * D + ks * 32 + q * 8];
    famv = fam[r0w + l];
  }

  // stage B-tile ct into buffer 0 (all 4 waves cooperate; 8 insts each)
  {
    const unsigned short* src = Eh + (long)ct * 64 * D;
#pragma unroll
    for (int t = 0; t < 8; ++t) {
      int c   = w * 512 + t * 64 + l;
      int row = c >> 5, ch = c & 31;
      ld_g2l16(src + row * D + ((ch ^ (row & 7)) << 3),
               &Bs[0][(w * 512 + t * 64) * 8]);
    }
  }

  int p = 0;
#pragma unroll 1
  for (int f = t0; f < t1; ++f) {
    __syncthreads();   // buf[p] filled (vmcnt drain); buf[1-p] free

    // next task coords; prefetch its B-tile into the other buffer
    int nrb = rb, nct = ct + 1;
    if (nct == nt) { ++nrb; nct = 4 * nrb; }
    if (f + 1 < t1) {
      const unsigned short* src = Eh + (long)nct * 64 * D;
#pragma unroll
      for (int t = 0; t < 8; ++t) {
        int c   = w * 512 + t * 64 + l;
        int row = c >> 5, ch = c & 31;
        ld_g2l16(src + row * D + ((ch ^ (row & 7)) << 3),
                 &Bs[p ^ 1][(w * 512 + t * 64) * 8]);
      }
    }

    if (rt <= ct) {
      const int famcv = fam[ct * 64 + l];
      floatx4 acc[4][4];
#pragma unroll
      for (int mi = 0; mi < 4; ++mi)
#pragma unroll
        for (int nj = 0; nj < 4; ++nj) acc[mi][nj] = (floatx4)0.0f;

      const unsigned short* bufp = &Bs[p][0];
#pragma unroll
      for (int ks = 0; ks < 8; ++ks) {
        half8 b[4];
#pragma unroll
        for (int nj = 0; nj < 4; ++nj) {
          int row = nj * 16 + m;
          b[nj] = *(const half8*)
              &bufp[row * 256 + (((ks * 4 + q) ^ (m & 7)) << 3)];
        }
#pragma unroll
        for (int mi = 0; mi < 4; ++mi)
#pragma unroll
          for (int nj = 0; nj < 4; ++nj)
            acc[mi][nj] = __builtin_amdgcn_mfma_f32_16x16x32_f16(
                apan[ks][mi], b[nj], acc[mi][nj], 0, 0, 0);
      }

      // ---- fused epilogue: row-side and col-side masked extremes ----
      int famR[16], famC[4];
#pragma unroll
      for (int mi = 0; mi < 4; ++mi)
#pragma unroll
        for (int r = 0; r < 4; ++r)
          famR[mi * 4 + r] = __shfl(famv, mi * 16 + q * 4 + r);
#pragma unroll
      for (int nj = 0; nj < 4; ++nj) famC[nj] = __shfl(famcv, nj * 16 + m);

      float rMin[16], rMax[16], cMin[4], cMax[4];
#pragma unroll
      for (int i = 0; i < 16; ++i) { rMin[i] = 4.0f; rMax[i] = -4.0f; }
#pragma unroll
      for (int j = 0; j < 4; ++j) { cMin[j] = 4.0f; cMax[j] = -4.0f; }

#pragma unroll
      for (int mi = 0; mi < 4; ++mi)
#pragma unroll
        for (int nj = 0; nj < 4; ++nj)
#pragma unroll
          for (int r = 0; r < 4; ++r) {
            float d = acc[mi][nj][r];        // C/D: col=l&15, row=q*4+r
            bool same = (famR[mi * 4 + r] == famC[nj]);
            float ds = same ? d : 4.0f;
            float dd = same ? -4.0f : d;
            rMin[mi * 4 + r] = fminf(rMin[mi * 4 + r], ds);
            rMax[mi * 4 + r] = fmaxf(rMax[mi * 4 + r], dd);
            cMin[nj] = fminf(cMin[nj], ds);
            cMax[nj] = fmaxf(cMax[nj], dd);
          }

      // row-side: reduce across the 16 col lanes (xor over m bits)
#pragma unroll
      for (int o = 1; o < 16; o <<= 1)
#pragma unroll
        for (int i = 0; i < 16; ++i) {
          rMin[i] = fminf(rMin[i], __shfl_xor(rMin[i], o));
          rMax[i] = fmaxf(rMax[i], __shfl_xor(rMax[i], o));
        }
      if (m == 0) {
        unsigned* dst = partial + ((long)rt * nt + ct) * 64;
#pragma unroll
        for (int mi = 0; mi < 4; ++mi)
#pragma unroll
          for (int r = 0; r < 4; ++r)
            dst[mi * 16 + q * 4 + r] =
                packmm(rMin[mi * 4 + r], rMax[mi * 4 + r]);
      }
      // col-side: reduce across the 4 q lanes (xor 16, 32); skip diagonal
#pragma unroll
      for (int o = 16; o < 64; o <<= 1)
#pragma unroll
        for (int j = 0; j < 4; ++j) {
          cMin[j] = fminf(cMin[j], __shfl_xor(cMin[j], o));
          cMax[j] = fmaxf(cMax[j], __shfl_xor(cMax[j], o));
        }
      if (q == 0 && rt != ct) {
        unsigned* dst = partial + ((long)ct * nt + rt) * 64;
#pragma unroll
        for (int nj = 0; nj < 4; ++nj)
          dst[nj * 16 + m] = packmm(cMin[nj], cMax[nj]);
      }
    }

    // A-panel reload if the span crosses into the next row-block
    if (f + 1 < t1 && nrb != rb) {
      const int r0w = (4 * nrb + w) * 64;
#pragma unroll
      for (int ks = 0; ks < 8; ++ks)
#pragma unroll
        for (int mi = 0; mi < 4; ++mi)
          apan[ks][mi] = *(const half8*)
              &Eh[(long)(r0w + mi * 16 + m) * D + ks * 32 + q * 8];
      famv = fam[r0w + l];
    }
    rb = nrb; ct = nct; rt = 4 * rb + w;
    p ^= 1;
  }
}

// K3: 4 threads per row combine nt contributor slots; grid reduce; last
// block writes the final mean (done-counter pattern).
__global__ __launch_bounds__(256) void reduce_kernel(
    const unsigned* __restrict__ partial, float* __restrict__ sumAcc,
    int* __restrict__ cntAcc, int* __restrict__ doneCnt,
    float* __restrict__ out, int B, int nt) {
  int gid = blockIdx.x * 256 + threadIdx.x;
  int row = gid >> 2;            // 4 threads per row
  int c   = gid & 3;
  int t = row >> 6, rl = row & 63;
  const unsigned* base = partial + ((long)t * nt) * 64 + rl;
  float mn = 4.0f, mx = -4.0f;
#pragma unroll 8
  for (int k = c; k < nt; k += 4) {
    unsigned pk = base[(long)k * 64];
    mn = fminf(mn, (float)__builtin_bit_cast(_Float16,
                                             (unsigned short)(pk & 0xFFFF)));
    mx = fmaxf(mx, (float)__builtin_bit_cast(_Float16,
                                             (unsigned short)(pk >> 16)));
  }
#pragma unroll
  for (int o = 1; o < 4; o <<= 1) {
    mn = fminf(mn, __shfl_xor(mn, o));
    mx = fmaxf(mx, __shfl_xor(mx, o));
  }
  float loss = 0.0f;
  int cc = 0;
  if (c == 0 && mn < 3.0f && mx > -3.0f) {   // has same && has diff
    loss = fmaxf(mx - mn + MARGIN, 0.0f);
    cc = 1;
  }
#pragma unroll
  for (int o = 1; o < 64; o <<= 1) {
    loss += __shfl_xor(loss, o);
    cc   += __shfl_xor(cc, o);
  }
  __shared__ float ls[4];
  __shared__ int   cs[4];
  if ((threadIdx.x & 63) == 0) {
    ls[threadIdx.x >> 6] = loss;
    cs[threadIdx.x >> 6] = cc;
  }
  __syncthreads();
  if (threadIdx.x == 0) {
    atomicAdd(sumAcc, ls[0] + ls[1] + ls[2] + ls[3]);
    atomicAdd(cntAcc, cs[0] + cs[1] + cs[2] + cs[3]);
    __threadfence();
    int old = atomicAdd(doneCnt, 1);
    if (old == (int)gridDim.x - 1) {
      float S = atomicAdd(sumAcc, 0.0f);   // coherent read
      int   C = atomicAdd(cntAcc, 0);
      out[0] = S / (float)(C > 0 ? C : 1);
    }
  }
}

extern "C" void kernel_launch(void* const* d_in, const int* in_sizes, int n_in,
                              void* d_out, int out_size, void* d_ws, size_t ws_size,
                              hipStream_t stream) {
  const float* E      = (const float*)d_in[0];
  const int*   labels = (const int*)d_in[1];
  float*       out    = (float*)d_out;
  const int B  = in_sizes[1];        // 8192
  const int nt = B / 64;             // 128 col tiles
  const int RB = nt / 4;             // 32 row-blocks of 256 rows
  const int nTasks = RB * nt - 2 * RB * (RB - 1);   // 2112 block-tasks

  // ws: Eh[B*D] fp16 (4MB) | fam[B] | partial[nt*nt*64] uint (4MB) | accums
  unsigned short* Eh = (unsigned short*)d_ws;
  int* fam           = (int*)(Eh + (size_t)B * D);
  unsigned* partial  = (unsigned*)(fam + B);
  float* sumAcc      = (float*)(partial + (size_t)nt * nt * 64);
  int* cntAcc        = (int*)(sumAcc + 1);
  int* doneCnt       = cntAcc + 1;

  prep_kernel<<<dim3(256), 256, 0, stream>>>(E, labels, Eh, fam,
                                             sumAcc, cntAcc, doneCnt, B);
  gram_kernel<<<dim3(512), 256, 0, stream>>>(Eh, fam, partial, nt, nTasks);
  reduce_kernel<<<dim3(B * 4 / 256), 256, 0, stream>>>(partial, sumAcc, cntAcc,
                                                       doneCnt, out, B, nt);
}

// Round 11
// 127.592 us; speedup vs baseline: 1.3557x; 1.1582x over previous
//
#include <hip/hip_runtime.h>

// ---------------------------------------------------------------------------
// HierarchicalAffinityLoss on MI355X, fp16-MFMA, round 11.
// loss = mean_r relu(maxDot_diff(r) - minDot_same(r) + 0.3), dots of
// row-normalized embeddings. Self-exclusion dropped (self-dot=1.0 never the
// min over ~2000 same-family dots near 0; verified rounds 3-10, absmax 0.0).
// Round-11: R10 traffic structure (A-panel in regs, B dbuf LDS, triangle)
// with the register budget FIXED: R10 ran at 236 VGPR + 64 AGPR = ~300/lane
// -> 1 wave/SIMD (8.35% occupancy) -> all latency exposed. Now: 32-row wave
// tiles (apan 64 VGPR, acc 32) -> ~200 regs -> 2 waves/SIMD, 2 blocks/CU.
// Col-side extremes merged across waves via LDS scratch inside the existing
// single-barrier task loop (merge task f-1 after barrier f). Prefetch issued
// AFTER the MFMA loop so compute ds_reads can't be ordered behind it.
// Col partials live in the unused lower triangle of the slot array.
// ---------------------------------------------------------------------------

typedef __attribute__((ext_vector_type(8))) _Float16 half8;  // MFMA A/B frag
typedef __attribute__((ext_vector_type(4))) float floatx4;   // MFMA C/D
typedef __attribute__((ext_vector_type(4))) unsigned short ushort4v;

constexpr int D = 256;   // embedding dim
#define MARGIN 0.3f
// packed family table {0,1,2,1,3,3}, 3 bits each
#define FAM_PACKED 111240

// async 16B global -> LDS (wave-uniform LDS base + lane*16)
static __device__ __forceinline__ void ld_g2l16(const unsigned short* g,
                                                unsigned short* l) {
  __builtin_amdgcn_global_load_lds(
      (const __attribute__((address_space(1))) unsigned int*)(const void*)g,
      (__attribute__((address_space(3))) unsigned int*)(void*)l, 16, 0, 0);
}

static __device__ __forceinline__ unsigned packmm(float mn, float mx) {
  unsigned lo = __builtin_bit_cast(unsigned short, (_Float16)mn);
  unsigned hi = __builtin_bit_cast(unsigned short, (_Float16)mx);
  return lo | (hi << 16);
}
static __device__ __forceinline__ float mmlo(unsigned p) {
  return (float)__builtin_bit_cast(_Float16, (unsigned short)(p & 0xFFFF));
}
static __device__ __forceinline__ float mmhi(unsigned p) {
  return (float)__builtin_bit_cast(_Float16, (unsigned short)(p >> 16));
}

// K1: grid-stride waves -> Eh[row][:] = fp16(E/||E||), fam[row]; zero accums
__global__ __launch_bounds__(256) void prep_kernel(
    const float* __restrict__ E, const int* __restrict__ labels,
    unsigned short* __restrict__ Eh, int* __restrict__ fam,
    float* __restrict__ sumAcc, int* __restrict__ cntAcc,
    int* __restrict__ doneCnt, int B) {
  if (blockIdx.x == 0 && threadIdx.x == 0) {
    sumAcc[0] = 0.0f; cntAcc[0] = 0; doneCnt[0] = 0;
  }
  int wave = blockIdx.x * 4 + (threadIdx.x >> 6);
  int lane = threadIdx.x & 63;
  int nw   = gridDim.x * 4;
  for (int row = wave; row < B; row += nw) {
    float4 v = *(const float4*)&E[(long)row * D + lane * 4];
    float s = v.x * v.x + v.y * v.y + v.z * v.z + v.w * v.w;
#pragma unroll
    for (int o = 1; o < 64; o <<= 1) s += __shfl_xor(s, o);
    float rn = 1.0f / sqrtf(s);
    ushort4v o4;
    o4.x = __builtin_bit_cast(unsigned short, (_Float16)(v.x * rn));
    o4.y = __builtin_bit_cast(unsigned short, (_Float16)(v.y * rn));
    o4.z = __builtin_bit_cast(unsigned short, (_Float16)(v.z * rn));
    o4.w = __builtin_bit_cast(unsigned short, (_Float16)(v.w * rn));
    *(ushort4v*)&Eh[(long)row * D + lane * 4] = o4;
    if (lane == 0) {
      int lab = labels[row];
      int labc = lab < 0 ? 0 : (lab > 5 ? 5 : lab);
      fam[row] = (lab < 6) ? ((FAM_PACKED >> (3 * labc)) & 7) : -1;
    }
  }
}

// K2: block = 4 waves; block owns 128-row A-panel (wave w: 32 rows, regs).
// Tasks (rb, ct), ct in [2rb, nt). Wave computes 32x64 tile vs col-tile ct
// iff its 64-row tile rt64 = 2rb+(w>>1) <= ct. B staged to dbuf LDS once per
// task; col-side extremes merged across waves via dbuf LDS scratch, written
// to the LOWER-triangle slot part[ct][rb] (row-side uses part[rt][ct>=rt]).
__global__ __launch_bounds__(256) void gram_kernel(
    const unsigned short* __restrict__ Eh, const int* __restrict__ fam,
    unsigned* __restrict__ part, int nt, int nTasks) {
  __shared__ unsigned short Bs[2][64 * 256];   // 2 x 32 KB
  __shared__ unsigned colS[2][4][64];          // 2 KB scratch

  const int tid = threadIdx.x;
  const int w = tid >> 6, l = tid & 63;
  const int m = l & 15, q = l >> 4;
  const int half = w & 1;

  // B-staging source offsets: LDS chunk c = w*512 + t*64 + l holds global
  // chunk (row=c>>5, kc=(c&31)^(row&7))  (XOR swizzle via source perm)
  int srcRel[8];
#pragma unroll
  for (int t = 0; t < 8; ++t) {
    int c = w * 512 + t * 64 + l;
    int row = c >> 5, ch = c & 31;
    srcRel[t] = row * D + ((ch ^ (row & 7)) << 3);
  }

  const int t0 = (int)(((long)blockIdx.x * nTasks) / gridDim.x);
  const int t1 = (int)(((long)(blockIdx.x + 1) * nTasks) / gridDim.x);

  // decode t0 -> (rb, ct): C(rb) = rb*(nt-rb+1); C(rb+1) = (rb+1)*(nt-rb)
  int rb = 0;
  while ((rb + 1) * (nt - rb) <= t0) ++rb;
  int ct = 2 * rb + (t0 - rb * (nt - rb + 1));

  half8 apan[8][2];
  int famv;
  {
    const int r0w = rb * 128 + w * 32;
#pragma unroll
    for (int ks = 0; ks < 8; ++ks)
#pragma unroll
      for (int mi = 0; mi < 2; ++mi)
        apan[ks][mi] = *(const half8*)
            &Eh[(long)(r0w + mi * 16 + m) * D + ks * 32 + q * 8];
    famv = fam[r0w + (l & 31)];
  }

  // stage first B-tile into buffer 0
  {
    const unsigned short* src = Eh + (long)ct * 64 * D;
#pragma unroll
    for (int t = 0; t < 8; ++t)
      ld_g2l16(src + srcRel[t], &Bs[0][(w * 512 + t * 64) * 8]);
  }

  int p = 0;
  int mct = -1, mrb = -1;   // pending col-merge coords (prev task)
#pragma unroll 1
  for (int f = t0; f < t1; ++f) {
    __syncthreads();   // buf[p] ready; prev colS writes visible

    // merge previous task's colS -> part[mct][mrb] (16 lanes per wave)
    if (mct >= 0 && l < 16) {
      const int sb = (f - 1) & 1;
      const int col = w * 16 + l;
      float mn = 4.0f, mx = -4.0f;
#pragma unroll
      for (int ww = 0; ww < 4; ++ww) {
        unsigned pk = colS[sb][ww][col];
        mn = fminf(mn, mmlo(pk));
        mx = fmaxf(mx, mmhi(pk));
      }
      part[((long)mct * nt + mrb) * 64 + col] = packmm(mn, mx);
    }

    const int rt64 = 2 * rb + (w >> 1);
    const bool doit = (rt64 <= ct);
    const int sb = f & 1;
    floatx4 acc[2][4];
#pragma unroll
    for (int mi = 0; mi < 2; ++mi)
#pragma unroll
      for (int nj = 0; nj < 4; ++nj) acc[mi][nj] = (floatx4)0.0f;

    if (doit) {
      const unsigned short* bufp = &Bs[p][0];
#pragma unroll
      for (int ks = 0; ks < 8; ++ks) {
        half8 b[4];
#pragma unroll
        for (int nj = 0; nj < 4; ++nj) {
          int row = nj * 16 + m;
          b[nj] = *(const half8*)
              &bufp[row * 256 + (((ks * 4 + q) ^ (m & 7)) << 3)];
        }
#pragma unroll
        for (int mi = 0; mi < 2; ++mi)
#pragma unroll
          for (int nj = 0; nj < 4; ++nj)
            acc[mi][nj] = __builtin_amdgcn_mfma_f32_16x16x32_f16(
                apan[ks][mi], b[nj], acc[mi][nj], 0, 0, 0);
      }
    }

    // prefetch next B AFTER this task's ds_reads (no false ordering)
    int nrb = rb, nct = ct + 1;
    if (nct == nt) { ++nrb; nct = 2 * nrb; }
    if (f + 1 < t1) {
      const unsigned short* src = Eh + (long)nct * 64 * D;
#pragma unroll
      for (int t = 0; t < 8; ++t)
        ld_g2l16(src + srcRel[t], &Bs[p ^ 1][(w * 512 + t * 64) * 8]);
    }

    if (doit) {
      // ---- epilogue: row-side + col-side masked extremes ----
      const int famcv = fam[ct * 64 + l];
      int famR[8], famC[4];
#pragma unroll
      for (int mi = 0; mi < 2; ++mi)
#pragma unroll
        for (int r = 0; r < 4; ++r)
          famR[mi * 4 + r] = __shfl(famv, mi * 16 + q * 4 + r);
#pragma unroll
      for (int nj = 0; nj < 4; ++nj) famC[nj] = __shfl(famcv, nj * 16 + m);

      float rMin[8], rMax[8], cMin[4], cMax[4];
#pragma unroll
      for (int i = 0; i < 8; ++i) { rMin[i] = 4.0f; rMax[i] = -4.0f; }
#pragma unroll
      for (int j = 0; j < 4; ++j) { cMin[j] = 4.0f; cMax[j] = -4.0f; }

#pragma unroll
      for (int mi = 0; mi < 2; ++mi)
#pragma unroll
        for (int nj = 0; nj < 4; ++nj)
#pragma unroll
          for (int r = 0; r < 4; ++r) {
            float d = acc[mi][nj][r];        // C/D: col=l&15, row=q*4+r
            bool same = (famR[mi * 4 + r] == famC[nj]);
            float ds = same ? d : 4.0f;
            float dd = same ? -4.0f : d;
            rMin[mi * 4 + r] = fminf(rMin[mi * 4 + r], ds);
            rMax[mi * 4 + r] = fmaxf(rMax[mi * 4 + r], dd);
            cMin[nj] = fminf(cMin[nj], ds);
            cMax[nj] = fmaxf(cMax[nj], dd);
          }

      // row-side: reduce across the 16 col lanes (xor over m bits)
#pragma unroll
      for (int o = 1; o < 16; o <<= 1)
#pragma unroll
        for (int i = 0; i < 8; ++i) {
          rMin[i] = fminf(rMin[i], __shfl_xor(rMin[i], o));
          rMax[i] = fmaxf(rMax[i], __shfl_xor(rMax[i], o));
        }
      if (m == 0) {
        unsigned* dst = part + ((long)rt64 * nt + ct) * 64;
#pragma unroll
        for (int mi = 0; mi < 2; ++mi)
#pragma unroll
          for (int r = 0; r < 4; ++r)
            dst[half * 32 + mi * 16 + q * 4 + r] =
                packmm(rMin[mi * 4 + r], rMax[mi * 4 + r]);
      }
      // col-side: reduce across the 4 q lanes; diag tile contributes sentinel
#pragma unroll
      for (int o = 16; o < 64; o <<= 1)
#pragma unroll
        for (int j = 0; j < 4; ++j) {
          cMin[j] = fminf(cMin[j], __shfl_xor(cMin[j], o));
          cMax[j] = fmaxf(cMax[j], __shfl_xor(cMax[j], o));
        }
      if (q == 0) {
        const bool real = (rt64 < ct);
#pragma unroll
        for (int nj = 0; nj < 4; ++nj)
          colS[sb][w][nj * 16 + m] =
              real ? packmm(cMin[nj], cMax[nj]) : packmm(4.0f, -4.0f);
      }
    } else {
      if (q == 0)
#pragma unroll
        for (int nj = 0; nj < 4; ++nj)
          colS[sb][w][nj * 16 + m] = packmm(4.0f, -4.0f);
    }

    mct = ct; mrb = rb;
    // A-panel reload when crossing into the next row-block
    if (f + 1 < t1 && nrb != rb) {
      const int r0w = nrb * 128 + w * 32;
#pragma unroll
      for (int ks = 0; ks < 8; ++ks)
#pragma unroll
        for (int mi = 0; mi < 2; ++mi)
          apan[ks][mi] = *(const half8*)
              &Eh[(long)(r0w + mi * 16 + m) * D + ks * 32 + q * 8];
      famv = fam[r0w + (l & 31)];
    }
    rb = nrb; ct = nct; p ^= 1;
  }
  // tail: merge the last task's colS
  __syncthreads();
  if (l < 16) {
    const int sb = (t1 - 1) & 1;
    const int col = w * 16 + l;
    float mn = 4.0f, mx = -4.0f;
#pragma unroll
    for (int ww = 0; ww < 4; ++ww) {
      unsigned pk = colS[sb][ww][col];
      mn = fminf(mn, mmlo(pk));
      mx = fmaxf(mx, mmhi(pk));
    }
    part[((long)mct * nt + mrb) * 64 + col] = packmm(mn, mx);
  }
}

// K3: 4 threads per row. Row-side: part[rt][k] for k in [rt, nt).
// Col-side: part[rt][rb] for rb in [0, rt>>1] (lower-triangle slots), rt>=1.
// Grid reduce; last block writes the final mean (done-counter pattern).
__global__ __launch_bounds__(256) void reduce_kernel(
    const unsigned* __restrict__ part, float* __restrict__ sumAcc,
    int* __restrict__ cntAcc, int* __restrict__ doneCnt,
    float* __restrict__ out, int B, int nt) {
  int gid = blockIdx.x * 256 + threadIdx.x;
  int row = gid >> 2;            // 4 threads per row
  int c   = gid & 3;
  int rt = row >> 6, rl = row & 63;
  const unsigned* base = part + ((long)rt * nt) * 64 + rl;
  float mn = 4.0f, mx = -4.0f;
  for (int k = rt + c; k < nt; k += 4) {
    unsigned pk = base[(long)k * 64];
    mn = fminf(mn, mmlo(pk));
    mx = fmaxf(mx, mmhi(pk));
  }
  if (rt >= 1) {
    int rbmax = rt >> 1;   // inclusive
    for (int k = c; k <= rbmax; k += 4) {
      unsigned pk = base[(long)k * 64];
      mn = fminf(mn, mmlo(pk));
      mx = fmaxf(mx, mmhi(pk));
    }
  }
#pragma unroll
  for (int o = 1; o < 4; o <<= 1) {
    mn = fminf(mn, __shfl_xor(mn, o));
    mx = fmaxf(mx, __shfl_xor(mx, o));
  }
  float loss = 0.0f;
  int cc = 0;
  if (c == 0 && mn < 3.0f && mx > -3.0f) {   // has same && has diff
    loss = fmaxf(mx - mn + MARGIN, 0.0f);
    cc = 1;
  }
#pragma unroll
  for (int o = 1; o < 64; o <<= 1) {
    loss += __shfl_xor(loss, o);
    cc   += __shfl_xor(cc, o);
  }
  __shared__ float ls[4];
  __shared__ int   cs[4];
  if ((threadIdx.x & 63) == 0) {
    ls[threadIdx.x >> 6] = loss;
    cs[threadIdx.x >> 6] = cc;
  }
  __syncthreads();
  if (threadIdx.x == 0) {
    atomicAdd(sumAcc, ls[0] + ls[1] + ls[2] + ls[3]);
    atomicAdd(cntAcc, cs[0] + cs[1] + cs[2] + cs[3]);
    __threadfence();
    int old = atomicAdd(doneCnt, 1);
    if (old == (int)gridDim.x - 1) {
      float S = atomicAdd(sumAcc, 0.0f);   // coherent read
      int   C = atomicAdd(cntAcc, 0);
      out[0] = S / (float)(C > 0 ? C : 1);
    }
  }
}

extern "C" void kernel_launch(void* const* d_in, const int* in_sizes, int n_in,
                              void* d_out, int out_size, void* d_ws, size_t ws_size,
                              hipStream_t stream) {
  const float* E      = (const float*)d_in[0];
  const int*   labels = (const int*)d_in[1];
  float*       out    = (float*)d_out;
  const int B  = in_sizes[1];        // 8192
  const int nt = B / 64;             // 128 col tiles
  const int RB = nt / 2;             // 64 row-blocks of 128 rows
  const int nTasks = RB * (nt - RB + 1);   // C(RB) = 64*65 = 4160 tasks

  // ws: Eh[B*D] fp16 (4MB) | fam[B] | part[nt*nt*64] uint (4MB) | accums
  unsigned short* Eh = (unsigned short*)d_ws;
  int* fam           = (int*)(Eh + (size_t)B * D);
  unsigned* part     = (unsigned*)(fam + B);
  float* sumAcc      = (float*)(part + (size_t)nt * nt * 64);
  int* cntAcc        = (int*)(sumAcc + 1);
  int* doneCnt       = cntAcc + 1;

  prep_kernel<<<dim3(256), 256, 0, stream>>>(E, labels, Eh, fam,
                                             sumAcc, cntAcc, doneCnt, B);
  gram_kernel<<<dim3(512), 256, 0, stream>>>(Eh, fam, part, nt, nTasks);
  reduce_kernel<<<dim3(B * 4 / 256), 256, 0, stream>>>(part, sumAcc, cntAcc,
                                                       doneCnt, out, B, nt);
}